// Round 6
// baseline (38442.398 us; speedup 1.0000x reference)
//
#include <hip/hip_runtime.h>
#include <hip/hip_cooperative_groups.h>
#include <math.h>

namespace cg = cooperative_groups;

#define B    32
#define H    1024
#define EMB  512
#define V    32000
#define SOS  1
#define NBLK 256
#define NTHR 1024
#define RPB  125            // vocab rows per block (V/NBLK exactly)

// ws float offsets. x/h layout: flat [k][b] (b contiguous).
#define OFF_X  0            // EMB*B = 16384
#define OFF_HA 16384        // H*B
#define OFF_HB 49152        // H*B
#define OFF_P  81920        // float4 [NBLK][B] softmax partials (m,l,am,0)
#define OFF_C  114688       // [T][B] log-softmax constants

typedef float f4v __attribute__((ext_vector_type(4)));

#define NEG_INF (-3.0e38f)

__global__ __launch_bounds__(NTHR, 4) void k_fused(
    const float* __restrict__ init_hidden,
    const float* __restrict__ emb,
    const float* __restrict__ wih, const float* __restrict__ bih,
    const float* __restrict__ whh, const float* __restrict__ bhh,
    const float* __restrict__ wout, const float* __restrict__ bout,
    float* __restrict__ out, float* __restrict__ ws, int T)
{
    cg::grid_group grid = cg::this_grid();
    const int t   = threadIdx.x;
    const int blk = blockIdx.x;
    const int gid = blk * NTHR + t;

    float* xG = ws + OFF_X;     // [EMB][B]
    float* hA = ws + OFF_HA;    // [H][B]
    float* hB = ws + OFF_HB;    // [H][B]

    __shared__ float  sred[4 * 1152];     // GRU reduce, stride-9 padded (18 KiB)
    __shared__ float4 fin[16 * 32];       // FIN1 per-wave partials (8 KiB)
    __shared__ float  f2m[256];
    __shared__ float  f2l[256];
    __shared__ int    f2a[256];
    __shared__ int    stok;

    // ---------------- init
    for (int i = gid; i < EMB * B; i += NBLK * NTHR)
        xG[i] = tanhf(emb[(size_t)SOS * EMB + (i >> 5)]);
    for (int i = gid; i < H * B; i += NBLK * NTHR) {
        int j = i >> 5, b = i & 31;
        hA[j * 32 + b] = init_hidden[(size_t)b * H + j];
    }
    grid.sync();

    for (int st = 0; st < T; ++st) {
        float* hold = (st & 1) ? hB : hA;
        float* hnew = (st & 1) ? hA : hB;
        float* orow = out + (size_t)st * B * V;

        // ================= GRU =================
        {
            const int ks = t >> 7;            // 8 k-slices of 192 over K=1536
            const int pl = t & 127;
            const int p  = blk * 128 + pl;
            const int b  = p & 31;
            const int j  = p >> 5;

            float ar = 0.f, az = 0.f, ain = 0.f, ahn = 0.f;
            const int k0 = ks * 192, k1 = k0 + 192;

            const int xe = (k1 < EMB) ? k1 : EMB;
            for (int k = k0; k < xe; k += 4) {
                const float u0 = xG[(k + 0) * 32 + b];
                const float u1 = xG[(k + 1) * 32 + b];
                const float u2 = xG[(k + 2) * 32 + b];
                const float u3 = xG[(k + 3) * 32 + b];
                const float4 w0 = *(const float4*)&wih[(size_t)(0 * H + j) * EMB + k];
                const float4 w1 = *(const float4*)&wih[(size_t)(1 * H + j) * EMB + k];
                const float4 w2 = *(const float4*)&wih[(size_t)(2 * H + j) * EMB + k];
                ar  = fmaf(w0.x, u0, fmaf(w0.y, u1, fmaf(w0.z, u2, fmaf(w0.w, u3, ar))));
                az  = fmaf(w1.x, u0, fmaf(w1.y, u1, fmaf(w1.z, u2, fmaf(w1.w, u3, az))));
                ain = fmaf(w2.x, u0, fmaf(w2.y, u1, fmaf(w2.z, u2, fmaf(w2.w, u3, ain))));
            }
            const int hs = (k0 > EMB) ? k0 : EMB;
            for (int k = hs; k < k1; k += 4) {
                const int kh = k - EMB;
                const float u0 = hold[(kh + 0) * 32 + b];
                const float u1 = hold[(kh + 1) * 32 + b];
                const float u2 = hold[(kh + 2) * 32 + b];
                const float u3 = hold[(kh + 3) * 32 + b];
                const float4 w0 = *(const float4*)&whh[(size_t)(0 * H + j) * H + kh];
                const float4 w1 = *(const float4*)&whh[(size_t)(1 * H + j) * H + kh];
                const float4 w2 = *(const float4*)&whh[(size_t)(2 * H + j) * H + kh];
                ar  = fmaf(w0.x, u0, fmaf(w0.y, u1, fmaf(w0.z, u2, fmaf(w0.w, u3, ar))));
                az  = fmaf(w1.x, u0, fmaf(w1.y, u1, fmaf(w1.z, u2, fmaf(w1.w, u3, az))));
                ahn = fmaf(w2.x, u0, fmaf(w2.y, u1, fmaf(w2.z, u2, fmaf(w2.w, u3, ahn))));
            }

            sred[0 * 1152 + pl * 9 + ks] = ar;
            sred[1 * 1152 + pl * 9 + ks] = az;
            sred[2 * 1152 + pl * 9 + ks] = ain;
            sred[3 * 1152 + pl * 9 + ks] = ahn;
            __syncthreads();

            if (t < 128) {
                const int pp = blk * 128 + t;
                const int bb = pp & 31, jj = pp >> 5;
                float s0 = 0.f, s1 = 0.f, s2 = 0.f, s3 = 0.f;
#pragma unroll
                for (int q = 0; q < 8; ++q) {
                    s0 += sred[0 * 1152 + t * 9 + q];
                    s1 += sred[1 * 1152 + t * 9 + q];
                    s2 += sred[2 * 1152 + t * 9 + q];
                    s3 += sred[3 * 1152 + t * 9 + q];
                }
                float gr  = s0 + bih[jj]         + bhh[jj];
                float gz  = s1 + bih[H + jj]     + bhh[H + jj];
                float gin = s2 + bih[2 * H + jj];
                float ghn = s3 + bhh[2 * H + jj];
                float r = 1.f / (1.f + expf(-gr));
                float z = 1.f / (1.f + expf(-gz));
                float n = tanhf(gin + r * ghn);   // r multiplies hh-part only
                const int hidx = jj * 32 + bb;
                hnew[hidx] = (1.f - z) * n + z * hold[hidx];
            }
            __syncthreads();   // sred reuse safety within block
        }
        grid.sync();

        // ================= PROJ: thread = (row, k-eighth), acc[32 b] partials =================
        {
            const int rr = t >> 3;             // 0..127 (row within block)
            const int s  = t & 7;              // k-split
            const bool rvalid = (rr < RPB);
            const int row = blk * RPB + (rvalid ? rr : (RPB - 1));   // clamp for safe loads
            const float* Wrow = wout + (size_t)row * H;

            float acc[32];
#pragma unroll
            for (int i = 0; i < 32; ++i) acc[i] = 0.f;

            for (int c = 0; c < 8; ++c) {
                const int kbase = c * 128 + s * 16;
                float4 w4[4];
#pragma unroll
                for (int q = 0; q < 4; ++q)
                    w4[q] = *(const float4*)&Wrow[kbase + q * 4];
#pragma unroll
                for (int kk = 0; kk < 16; ++kk) {
                    const float wv = ((const float*)&w4[kk >> 2])[kk & 3];
                    const float* hrow = hnew + (size_t)(kbase + kk) * 32;
#pragma unroll
                    for (int bb = 0; bb < 8; ++bb) {
                        const float4 hv = *(const float4*)&hrow[bb * 4];
                        acc[bb * 4 + 0] = fmaf(wv, hv.x, acc[bb * 4 + 0]);
                        acc[bb * 4 + 1] = fmaf(wv, hv.y, acc[bb * 4 + 1]);
                        acc[bb * 4 + 2] = fmaf(wv, hv.z, acc[bb * 4 + 2]);
                        acc[bb * 4 + 3] = fmaf(wv, hv.w, acc[bb * 4 + 3]);
                    }
                }
            }

            // butterfly-sum the 8 k-partials (s lives in lane bits 0..2)
#pragma unroll
            for (int i = 0; i < 32; ++i) {
                acc[i] += __shfl_xor(acc[i], 1);
                acc[i] += __shfl_xor(acc[i], 2);
                acc[i] += __shfl_xor(acc[i], 4);
            }

            const float bo = bout[row];
#pragma unroll
            for (int i = 0; i < 32; ++i) acc[i] += bo;

            // store logits: lane (rr,s) owns b in {4s..4s+3}
            if (rvalid) {
#pragma unroll
                for (int j = 0; j < 4; ++j)
                    __builtin_nontemporal_store(acc[s * 4 + j],
                        &orow[(size_t)(s * 4 + j) * V + row]);
            }

            // FIN1: per-b online (m, l=sum exp, argmax) across this wave's 8 rows
            const int wv_ = t >> 6;            // wave id 0..15
#pragma unroll
            for (int i = 0; i < 32; ++i) {
                float m = rvalid ? acc[i] : NEG_INF;
                float l = rvalid ? 1.0f : 0.0f;
                int   a = rvalid ? row : 0x7FFFFFFF;
#pragma unroll
                for (int mask = 8; mask <= 32; mask <<= 1) {
                    const float om = __shfl_xor(m, mask);
                    const float ol = __shfl_xor(l, mask);
                    const int   oa = __shfl_xor(a, mask);
                    const bool take = (om > m) || (om == m && oa < a);
                    const float mn = take ? om : m;
                    const int   an = take ? oa : a;
                    l = l * expf(m - mn) + ol * expf(om - mn);
                    m = mn; a = an;
                }
                if ((t & 63) == 0) fin[wv_ * 32 + i] = make_float4(m, l, (float)a, 0.f);
            }
            __syncthreads();

            // block-combine 16 wave-partials per b, write grid partials
            if (t < 32) {
                float4 p0 = fin[t];
                float m = p0.x; float l = p0.y; int a = (int)p0.z;
                for (int w2 = 1; w2 < 16; ++w2) {
                    float4 p = fin[w2 * 32 + t];
                    const float om = p.x, ol = p.y; const int oa = (int)p.z;
                    const bool take = (om > m) || (om == m && oa < a);
                    const float mn = take ? om : m;
                    const int   an = take ? oa : a;
                    l = l * expf(m - mn) + ol * expf(om - mn);
                    m = mn; a = an;
                }
                ((float4*)(ws + OFF_P))[blk * 32 + t] = make_float4(m, l, (float)a, 0.f);
            }
            __syncthreads();
        }
        grid.sync();

        // ================= FIN2: combine 256 block-partials per b =================
        if (blk < B) {
            const int b = blk;
            if (t < 256) {
                float4 p = ((const float4*)(ws + OFF_P))[t * 32 + b];
                f2m[t] = p.x; f2l[t] = p.y; f2a[t] = (int)p.z;
            }
            __syncthreads();
            for (int sft = 128; sft > 0; sft >>= 1) {
                if (t < sft) {
                    const float om = f2m[t + sft], ol = f2l[t + sft];
                    const int   oa = f2a[t + sft];
                    float m = f2m[t]; float l = f2l[t]; int a = f2a[t];
                    const bool take = (om > m) || (om == m && oa < a);
                    const float mn = take ? om : m;
                    const int   an = take ? oa : a;
                    l = l * expf(m - mn) + ol * expf(om - mn);
                    f2m[t] = mn; f2l[t] = l; f2a[t] = an;
                }
                __syncthreads();
            }
            if (t == 0) {
                ws[OFF_C + st * 32 + b] = f2m[0] + logf(f2l[0]);
                stok = f2a[0];
            }
            __syncthreads();
            const int TOK = stok;
            if (t < EMB)
                xG[t * 32 + b] = tanhf(emb[(size_t)TOK * EMB + t]);
        }
        grid.sync();
    }

    // ================= deferred log-softmax subtract (nt streams) =================
    for (int r = blk; r < T * B; r += NBLK) {
        const float Cc = ws[OFF_C + r];
        f4v* row = (f4v*)(out + (size_t)r * V);
        for (int v4 = t; v4 < V / 4; v4 += NTHR) {
            f4v x = __builtin_nontemporal_load(&row[v4]);
            x -= Cc;
            __builtin_nontemporal_store(x, &row[v4]);
        }
    }
}

extern "C" void kernel_launch(void* const* d_in, const int* in_sizes, int n_in,
                              void* d_out, int out_size, void* d_ws, size_t ws_size,
                              hipStream_t stream)
{
    const float* p_ih   = (const float*)d_in[0];
    // d_in[1] encoder_outputs unused; d_in[2] tgt_len recovered from out_size
    const float* p_emb  = (const float*)d_in[3];
    const float* p_wih  = (const float*)d_in[4];
    const float* p_bih  = (const float*)d_in[5];
    const float* p_whh  = (const float*)d_in[6];
    const float* p_bhh  = (const float*)d_in[7];
    const float* p_wout = (const float*)d_in[8];
    const float* p_bout = (const float*)d_in[9];
    float* p_out = (float*)d_out;
    float* p_ws  = (float*)d_ws;
    int T = out_size / (B * V);

    void* args[] = { &p_ih, &p_emb, &p_wih, &p_bih, &p_whh, &p_bhh,
                     &p_wout, &p_bout, &p_out, &p_ws, &T };
    hipLaunchCooperativeKernel((void*)k_fused, dim3(NBLK), dim3(NTHR), args, 0, stream);
}

// Round 7
// 5660.494 us; speedup vs baseline: 6.7914x; 6.7914x over previous
//
#include <hip/hip_runtime.h>
#include <math.h>

#define B    32
#define H    1024
#define EMB  512
#define V    32000
#define SOS  1

// ws float offsets. x/h layout: [k][b], b contiguous.
#define OFF_X  0            // EMB*B = 16384
#define OFF_HA 16384        // H*B
#define OFF_HB 49152        // H*B
#define OFF_P  81920        // float4[250][32] = 32000 floats
#define OFF_C  113920       // [T][B]

#define NEG_INF (-3.0e38f)

typedef float f4v __attribute__((ext_vector_type(4)));

// ---------------------------------------------------------------- INIT
__global__ void k_init(const float* __restrict__ ih, const float* __restrict__ emb,
                       float* __restrict__ ws)
{
    int idx = blockIdx.x * blockDim.x + threadIdx.x;
    int stride = gridDim.x * blockDim.x;
    for (int i = idx; i < EMB * B; i += stride)
        ws[OFF_X + i] = tanhf(emb[(size_t)SOS * EMB + (i >> 5)]);
    for (int i = idx; i < H * B; i += stride) {
        int j = i >> 5, b = i & 31;
        ws[OFF_HA + j * 32 + b] = ih[(size_t)b * H + j];
    }
}

// ---------------------------------------------------------------- GRU (256 blocks x 1024) — proven round-5 body
__global__ __launch_bounds__(1024) void k_gru(
    const float* __restrict__ xG, const float* __restrict__ hold,
    const float* __restrict__ wih, const float* __restrict__ bih,
    const float* __restrict__ whh, const float* __restrict__ bhh,
    float* __restrict__ hnew)
{
    const int t   = threadIdx.x;
    const int blk = blockIdx.x;
    __shared__ float sred[4 * 1152];

    const int ks = t >> 7;
    const int pl = t & 127;
    const int p  = blk * 128 + pl;
    const int b  = p & 31;
    const int j  = p >> 5;

    float ar = 0.f, az = 0.f, ain = 0.f, ahn = 0.f;
    const int k0 = ks * 192, k1 = k0 + 192;

    const int xe = (k1 < EMB) ? k1 : EMB;
    for (int k = k0; k < xe; k += 4) {
        const float u0 = xG[(k + 0) * 32 + b];
        const float u1 = xG[(k + 1) * 32 + b];
        const float u2 = xG[(k + 2) * 32 + b];
        const float u3 = xG[(k + 3) * 32 + b];
        const float4 w0 = *(const float4*)&wih[(size_t)(0 * H + j) * EMB + k];
        const float4 w1 = *(const float4*)&wih[(size_t)(1 * H + j) * EMB + k];
        const float4 w2 = *(const float4*)&wih[(size_t)(2 * H + j) * EMB + k];
        ar  = fmaf(w0.x, u0, fmaf(w0.y, u1, fmaf(w0.z, u2, fmaf(w0.w, u3, ar))));
        az  = fmaf(w1.x, u0, fmaf(w1.y, u1, fmaf(w1.z, u2, fmaf(w1.w, u3, az))));
        ain = fmaf(w2.x, u0, fmaf(w2.y, u1, fmaf(w2.z, u2, fmaf(w2.w, u3, ain))));
    }
    const int hs = (k0 > EMB) ? k0 : EMB;
    for (int k = hs; k < k1; k += 4) {
        const int kh = k - EMB;
        const float u0 = hold[(kh + 0) * 32 + b];
        const float u1 = hold[(kh + 1) * 32 + b];
        const float u2 = hold[(kh + 2) * 32 + b];
        const float u3 = hold[(kh + 3) * 32 + b];
        const float4 w0 = *(const float4*)&whh[(size_t)(0 * H + j) * H + kh];
        const float4 w1 = *(const float4*)&whh[(size_t)(1 * H + j) * H + kh];
        const float4 w2 = *(const float4*)&whh[(size_t)(2 * H + j) * H + kh];
        ar  = fmaf(w0.x, u0, fmaf(w0.y, u1, fmaf(w0.z, u2, fmaf(w0.w, u3, ar))));
        az  = fmaf(w1.x, u0, fmaf(w1.y, u1, fmaf(w1.z, u2, fmaf(w1.w, u3, az))));
        ahn = fmaf(w2.x, u0, fmaf(w2.y, u1, fmaf(w2.z, u2, fmaf(w2.w, u3, ahn))));
    }

    sred[0 * 1152 + pl * 9 + ks] = ar;
    sred[1 * 1152 + pl * 9 + ks] = az;
    sred[2 * 1152 + pl * 9 + ks] = ain;
    sred[3 * 1152 + pl * 9 + ks] = ahn;
    __syncthreads();

    if (t < 128) {
        const int pp = blk * 128 + t;
        const int bb = pp & 31, jj = pp >> 5;
        float s0 = 0.f, s1 = 0.f, s2 = 0.f, s3 = 0.f;
#pragma unroll
        for (int q = 0; q < 8; ++q) {
            s0 += sred[0 * 1152 + t * 9 + q];
            s1 += sred[1 * 1152 + t * 9 + q];
            s2 += sred[2 * 1152 + t * 9 + q];
            s3 += sred[3 * 1152 + t * 9 + q];
        }
        float gr  = s0 + bih[jj]         + bhh[jj];
        float gz  = s1 + bih[H + jj]     + bhh[H + jj];
        float gin = s2 + bih[2 * H + jj];
        float ghn = s3 + bhh[2 * H + jj];
        float r = 1.f / (1.f + expf(-gr));
        float z = 1.f / (1.f + expf(-gz));
        float n = tanhf(gin + r * ghn);   // r multiplies hh-part only
        const int hidx = jj * 32 + bb;
        hnew[hidx] = (1.f - z) * n + z * hold[hidx];
    }
}

// ---------------------------------------------------------------- PROJ
// 250 blocks x 512 thr; tile 128 rows x 32 b; thread (rg16,bg4,ks8): R=8,C=8, 4k/chunk.
// W LDS [2][128][36] (pad-9-quads), h LDS [2][32][32]; Red [256][68] k-reduce tree.
#define PW  (128 * 36)          // 4608 floats per W buffer
#define DSM_BYTES ((2 * PW + 2 * 1024 + 256 * 68) * 4)   // 36864+8192+69632 = 114688

__global__ __launch_bounds__(512, 2) void k_proj(
    const float* __restrict__ h, const float* __restrict__ wout,
    const float* __restrict__ bout, float* __restrict__ orow,
    float4* __restrict__ partial)
{
    extern __shared__ __align__(16) float dsm[];
    float* Wl  = dsm;               // [2][PW]
    float* Hl  = dsm + 2 * PW;      // [2][1024]
    float* Red = Hl + 2048;         // [256][68]

    const int t   = threadIdx.x;
    const int blk = blockIdx.x;
    const int r0  = blk * 128;

    const int bg = t & 3;           // 8-b group
    const int rg = (t >> 2) & 15;   // row group (rows rg+16i)
    const int ks = t >> 6;          // k-eighth (wave id)

    // W staging: thread covers row srow, quads sq,sq+1 (32B)
    const int srow = t >> 2;        // 0..127
    const int sq   = (t & 3) * 2;
    const float* gWp = wout + (size_t)(r0 + srow) * H + sq * 4;
    const int lW = srow * 36 + sq * 4;
    // h staging (t<256): k=t>>3, b=(t&7)*4
    const int hk = t >> 3, hb = (t & 7) * 4;

    float acc[8][8];
#pragma unroll
    for (int i = 0; i < 8; ++i)
#pragma unroll
        for (int j = 0; j < 8; ++j) acc[i][j] = 0.f;

    // prologue: stage chunk 0
    {
        float4 w0 = *(const float4*)&gWp[0];
        float4 w1 = *(const float4*)&gWp[4];
        *(float4*)&Wl[lW] = w0;
        *(float4*)&Wl[lW + 4] = w1;
        if (t < 256) {
            float4 hv = *(const float4*)&h[hk * 32 + hb];
            *(float4*)&Hl[hk * 32 + hb] = hv;
        }
    }
    __syncthreads();

    for (int c = 0; c < 32; ++c) {
        const int cur = c & 1;
        float4 pw0, pw1, ph;
        if (c + 1 < 32) {
            pw0 = *(const float4*)&gWp[(c + 1) * 32];
            pw1 = *(const float4*)&gWp[(c + 1) * 32 + 4];
            if (t < 256) ph = *(const float4*)&h[(c + 1) * 1024 + hk * 32 + hb];
        }
        const float* wb = Wl + cur * PW;
        const float* hc = Hl + cur * 1024;

        float4 hv[4][2];
#pragma unroll
        for (int j = 0; j < 4; ++j) {
            hv[j][0] = *(const float4*)&hc[(ks * 4 + j) * 32 + bg * 8];
            hv[j][1] = *(const float4*)&hc[(ks * 4 + j) * 32 + bg * 8 + 4];
        }
#pragma unroll
        for (int i = 0; i < 8; ++i) {
            const int r = rg + 16 * i;
            const float4 wv = *(const float4*)&wb[r * 36 + ks * 4];
#pragma unroll
            for (int j = 0; j < 4; ++j) {
                const float wf = (j == 0) ? wv.x : (j == 1) ? wv.y : (j == 2) ? wv.z : wv.w;
                acc[i][0] = fmaf(wf, hv[j][0].x, acc[i][0]);
                acc[i][1] = fmaf(wf, hv[j][0].y, acc[i][1]);
                acc[i][2] = fmaf(wf, hv[j][0].z, acc[i][2]);
                acc[i][3] = fmaf(wf, hv[j][0].w, acc[i][3]);
                acc[i][4] = fmaf(wf, hv[j][1].x, acc[i][4]);
                acc[i][5] = fmaf(wf, hv[j][1].y, acc[i][5]);
                acc[i][6] = fmaf(wf, hv[j][1].z, acc[i][6]);
                acc[i][7] = fmaf(wf, hv[j][1].w, acc[i][7]);
            }
        }
        if (c + 1 < 32) {
            float* wn = Wl + (cur ^ 1) * PW;
            *(float4*)&wn[lW] = pw0;
            *(float4*)&wn[lW + 4] = pw1;
            if (t < 256) *(float4*)&Hl[(cur ^ 1) * 1024 + hk * 32 + hb] = ph;
        }
        __syncthreads();
    }

    // ---- k-reduce tree over ks (Red stride 68: quad-class spreads by slot)
#define RED_ST(slot)                                                          \
    {                                                                         \
        float* rp = Red + (slot) * 68;                                        \
        _Pragma("unroll")                                                     \
        for (int i = 0; i < 8; ++i) {                                         \
            *(float4*)&rp[i * 8]     = make_float4(acc[i][0], acc[i][1], acc[i][2], acc[i][3]); \
            *(float4*)&rp[i * 8 + 4] = make_float4(acc[i][4], acc[i][5], acc[i][6], acc[i][7]); \
        }                                                                     \
    }
#define RED_ADD()                                                             \
    {                                                                         \
        const float* rp = Red + t * 68;                                       \
        _Pragma("unroll")                                                     \
        for (int i = 0; i < 8; ++i) {                                         \
            const float4 a0 = *(const float4*)&rp[i * 8];                     \
            const float4 a1 = *(const float4*)&rp[i * 8 + 4];                 \
            acc[i][0] += a0.x; acc[i][1] += a0.y; acc[i][2] += a0.z; acc[i][3] += a0.w; \
            acc[i][4] += a1.x; acc[i][5] += a1.y; acc[i][6] += a1.z; acc[i][7] += a1.w; \
        }                                                                     \
    }

    if (ks >= 4) RED_ST(t - 256);
    __syncthreads();
    if (ks < 4) RED_ADD();
    __syncthreads();
    if (ks == 2 || ks == 3) RED_ST(t - 128);
    __syncthreads();
    if (ks < 2) RED_ADD();
    __syncthreads();
    if (ks == 1) RED_ST(t - 64);
    __syncthreads();

    if (ks == 0) {
        RED_ADD();
        // bias + nt-store raw logits
#pragma unroll
        for (int i = 0; i < 8; ++i) {
            const int r = r0 + rg + 16 * i;
            const float bo = bout[r];
#pragma unroll
            for (int j = 0; j < 8; ++j) {
                acc[i][j] += bo;
                __builtin_nontemporal_store(acc[i][j],
                    &orow[(size_t)(bg * 8 + j) * V + r]);
            }
        }
        // FIN1: online (m, sum-exp, argmax) over this thread's 8 rows, per b
        float m[8], l[8]; int a[8];
#pragma unroll
        for (int j = 0; j < 8; ++j) {
            m[j] = acc[0][j]; a[j] = r0 + rg; l[j] = 1.0f;
#pragma unroll
            for (int i = 1; i < 8; ++i) {
                const float x = acc[i][j];
                if (x > m[j]) {
                    l[j] = l[j] * expf(m[j] - x) + 1.0f;
                    m[j] = x; a[j] = r0 + rg + 16 * i;
                } else {
                    l[j] += expf(x - m[j]);
                }
            }
        }
        // cross-rg merge (lane bits 2..5)
#pragma unroll
        for (int mk = 4; mk <= 32; mk <<= 1) {
#pragma unroll
            for (int j = 0; j < 8; ++j) {
                const float om = __shfl_xor(m[j], mk);
                const float ol = __shfl_xor(l[j], mk);
                const int   oa = __shfl_xor(a[j], mk);
                const bool take = (om > m[j]) || (om == m[j] && oa < a[j]);
                const float mn = take ? om : m[j];
                const int   an = take ? oa : a[j];
                l[j] = l[j] * expf(m[j] - mn) + ol * expf(om - mn);
                m[j] = mn; a[j] = an;
            }
        }
        if (rg == 0) {
#pragma unroll
            for (int j = 0; j < 8; ++j)
                partial[blk * 32 + bg * 8 + j] = make_float4(m[j], l[j], (float)a[j], 0.f);
        }
    }
}

// ---------------------------------------------------------------- FIN2 (32 blocks x 256)
__global__ __launch_bounds__(256) void k_fin2(
    const float4* __restrict__ partial, const float* __restrict__ emb,
    float* __restrict__ xG, float* __restrict__ C)
{
    const int b = blockIdx.x;
    const int t = threadIdx.x;
    __shared__ float fm[256], fl[256];
    __shared__ int   fa[256], stok;

    float m = NEG_INF, l = 0.f; int a = 0x7FFFFFFF;
    if (t < 250) {
        float4 p = partial[t * 32 + b];
        m = p.x; l = p.y; a = (int)p.z;
    }
    fm[t] = m; fl[t] = l; fa[t] = a;
    __syncthreads();
    for (int s = 128; s > 0; s >>= 1) {
        if (t < s) {
            const float om = fm[t + s], ol = fl[t + s];
            const int   oa = fa[t + s];
            float mm = fm[t]; float ll = fl[t]; int aa = fa[t];
            const bool take = (om > mm) || (om == mm && oa < aa);
            const float mn = take ? om : mm;
            const int   an = take ? oa : aa;
            ll = ll * expf(mm - mn) + ol * expf(om - mn);
            fm[t] = mn; fl[t] = ll; fa[t] = an;
        }
        __syncthreads();
    }
    if (t == 0) {
        C[b] = fm[0] + logf(fl[0]);
        stok = fa[0];
    }
    __syncthreads();
    const int TOK = stok;
    for (int k = t; k < EMB; k += 256)
        xG[k * 32 + b] = tanhf(emb[(size_t)TOK * EMB + k]);
}

// ---------------------------------------------------------------- deferred subtract
__global__ __launch_bounds__(256) void k_sub(float* __restrict__ out,
                                             const float* __restrict__ C)
{
    const int r = blockIdx.x;
    const float c = C[r];
    f4v* row = (f4v*)(out + (size_t)r * V);
    for (int v = threadIdx.x; v < V / 4; v += 256) {
        f4v x = __builtin_nontemporal_load(&row[v]);
        x -= c;
        __builtin_nontemporal_store(x, &row[v]);
    }
}

// ---------------------------------------------------------------- launch
extern "C" void kernel_launch(void* const* d_in, const int* in_sizes, int n_in,
                              void* d_out, int out_size, void* d_ws, size_t ws_size,
                              hipStream_t stream)
{
    const float* p_ih   = (const float*)d_in[0];
    // d_in[1] encoder_outputs unused; d_in[2] tgt_len recovered from out_size
    const float* p_emb  = (const float*)d_in[3];
    const float* p_wih  = (const float*)d_in[4];
    const float* p_bih  = (const float*)d_in[5];
    const float* p_whh  = (const float*)d_in[6];
    const float* p_bhh  = (const float*)d_in[7];
    const float* p_wout = (const float*)d_in[8];
    const float* p_bout = (const float*)d_in[9];
    float* out = (float*)d_out;
    float* ws  = (float*)d_ws;
    const int T = out_size / (B * V);

    float*  xG = ws + OFF_X;
    float*  hA = ws + OFF_HA;
    float*  hB = ws + OFF_HB;
    float4* P  = (float4*)(ws + OFF_P);
    float*  C  = ws + OFF_C;

    hipFuncSetAttribute((const void*)k_proj,
                        hipFuncAttributeMaxDynamicSharedMemorySize, DSM_BYTES);

    k_init<<<64, 256, 0, stream>>>(p_ih, p_emb, ws);

    for (int st = 0; st < T; ++st) {
        float* hold = (st & 1) ? hB : hA;
        float* hnew = (st & 1) ? hA : hB;
        float* orow = out + (size_t)st * B * V;
        k_gru<<<256, 1024, 0, stream>>>(xG, hold, p_wih, p_bih, p_whh, p_bhh, hnew);
        k_proj<<<250, 512, DSM_BYTES, stream>>>(hnew, p_wout, p_bout, orow, P);
        k_fin2<<<B, 256, 0, stream>>>(P, p_emb, xG, C + st * B);
    }
    k_sub<<<T * B, 256, 0, stream>>>(out, C);
}